// Round 7
// baseline (111.961 us; speedup 1.0000x reference)
//
#include <hip/hip_runtime.h>
#include <stdint.h>

#define BB 256
#define CC 64
#define CVV 4
#define LL 2048
#define NBLK 2                    // fused gather blocks per batch
#define NRG ((CC + CVV) / NBLK)   // 34 rows per fused block
#define GROUPS 4                  // fallback gather blocks per batch
#define NRGF ((CC + CVV) / GROUPS)
#define FLAG_STRIDE 16            // ints -> 64 B per flag
#define FLAGS_BYTES (BB * FLAG_STRIDE * 4)
#define STAGE_BYTES ((size_t)BB * LL * 4)

#define WAITV(n) asm volatile("s_waitcnt vmcnt(" #n ")" ::: "memory")

__device__ __forceinline__ void ce_desc(unsigned long long* key, int i, int j,
                                        bool descBlk) {
  unsigned long long a = key[i], c = key[j];
  bool sw = descBlk ? (a < c) : (a > c);
  if (sw) { key[i] = c; key[j] = a; }
}

// ---------------------------------------------------------------------------
// Fused kernel. Block = (batch b, half g), 512 threads.
// First block of a batch to CAS flag[b] 0->1 runs the per-batch bitonic
// argsort (stable descending on ord(rand_f)<<32 | (L-1-idx)), writes stage
// ints + mask_t, release-stores flag=2 (agent scope). The sibling spins
// (acquire) then reads stage. Deadlock-free under any dispatch order: a
// spinner exists only if its claimer is resident and making progress.
// Gather: 34 rows via 5-slot LDS ring (40 KB) fed by global_load_lds,
// depth-3, counted vmcnt, one raw s_barrier per row. Rows 0-2 are issued
// into slots 2-4 (bytes 16K..40K) BEFORE the claim: the sort's key[] lives
// in bytes 0..16K, so prefetch and sort never clash.
// ---------------------------------------------------------------------------
__global__ __launch_bounds__(512) void trimmer_fused(
    const float* __restrict__ x, const float* __restrict__ v,
    const void* __restrict__ mask, const float* __restrict__ rnd,
    float* __restrict__ xo, float* __restrict__ vo, float* __restrict__ mo,
    int* __restrict__ stage, int* __restrict__ flags) {
  __shared__ union {
    unsigned long long key[LL];   // bytes [0, 16K)
    float ring[5][LL];            // 5 slots x 8 KB = 40 KB
  } sh;
  __shared__ int cnt;
  __shared__ unsigned detf;
  __shared__ int role;

  const int gid = blockIdx.x;
  const int b = gid >> 1;
  const int g = gid & 1;
  const int tid = threadIdx.x;
  const int w = tid >> 6;
  const int lane = tid & 63;

  const float* const xs = x + (size_t)b * CC * LL;
  const float* const vs = v + (size_t)b * CVV * LL;
  float* const xd = xo + (size_t)b * CC * LL;
  float* const vd = vo + (size_t)b * CVV * LL;

#define SRCROW(rr) ((g * NRG + (rr)) < CC \
    ? xs + (size_t)(g * NRG + (rr)) * LL \
    : vs + (size_t)(g * NRG + (rr) - CC) * LL)
#define DSTROW(rr) ((g * NRG + (rr)) < CC \
    ? xd + (size_t)(g * NRG + (rr)) * LL \
    : vd + (size_t)(g * NRG + (rr) - CC) * LL)
  // row rr lives in slot (rr+2) % 5: rows 0-2 -> slots 2,3,4 (clash-free
  // with key[]). One global_load_lds per wave per row (1 KB slice).
#define ISSUE(rr, slot) do { \
    const float* _src = SRCROW(rr) + w * 256 + lane * 4; \
    float* _dst = &sh.ring[(slot)][0] + w * 256; \
    __builtin_amdgcn_global_load_lds( \
        (const __attribute__((address_space(1))) void*)_src, \
        (__attribute__((address_space(3))) void*)_dst, 16, 0, 0); \
  } while (0)

  ISSUE(0, 2); ISSUE(1, 3); ISSUE(2, 4);  // prefetch under the claim/sort

  // ---- claim / spin ----
  if (tid == 0) {
    int* f = &flags[b * FLAG_STRIDE];
    int st = __hip_atomic_load(f, __ATOMIC_ACQUIRE, __HIP_MEMORY_SCOPE_AGENT);
    int r;
    if (st == 0) {
      int exp = 0;
      r = __hip_atomic_compare_exchange_strong(f, &exp, 1, __ATOMIC_ACQUIRE,
              __ATOMIC_ACQUIRE, __HIP_MEMORY_SCOPE_AGENT) ? 0 : 2;
    } else r = (st == 2) ? 1 : 2;
    if (r == 2) {
      while (__hip_atomic_load(f, __ATOMIC_ACQUIRE,
                               __HIP_MEMORY_SCOPE_AGENT) != 2)
        __builtin_amdgcn_s_sleep(4);
      r = 1;
    }
    role = r; cnt = 0; detf = 0;
  }
  __syncthreads();  // drains vmcnt (rows 0-2 land); broadcasts role

  int4 s;  // this thread's perm entries for output positions 4*tid..4*tid+3
  if (role == 0) {
    // ---------------- sort (this block won the claim) ----------------
    { unsigned val = ((const unsigned*)mask)[b * 512 + tid];
      unsigned f2 = (val == 0x3F800000u) ? 2u : (val > 1u ? 1u : 0u);
      if (f2) atomicOr(&detf, f2); }
    __syncthreads();
    const unsigned fl = detf;
    const int layout = (fl & 1u) ? 1 : ((fl & 2u) ? 2 : 0);

    int local = 0;
    for (int l = tid; l < LL; l += 512) {
      bool m;
      if (layout == 1)      m = ((const unsigned char*)mask)[b * LL + l] != 0;
      else if (layout == 2) m = ((const float*)mask)[b * LL + l] != 0.0f;
      else                  m = ((const int*)mask)[b * LL + l] != 0;
      float rf = m ? -1.0f : rnd[b * LL + l];
      unsigned u = __float_as_uint(rf);
      u = (u & 0x80000000u) ? ~u : (u | 0x80000000u);  // order-preserving
      sh.key[l] = ((unsigned long long)u << 32) | (unsigned)(LL - 1 - l);
      local += m ? 1 : 0;
    }
    if (local) atomicAdd(&cnt, local);
    __syncthreads();

    for (int size = 2; size <= 256; size <<= 1) {
      for (int stride = size >> 1; stride > 0; stride >>= 1) {
#pragma unroll
        for (int pp = 0; pp < 2; ++pp) {
          int p = w * 128 + pp * 64 + lane;
          int i = ((p & ~(stride - 1)) << 1) | (p & (stride - 1));
          ce_desc(sh.key, i, i + stride, (i & size) == 0);
        }
        __builtin_amdgcn_wave_barrier();
      }
    }
    __syncthreads();
    for (int size = 512; size <= 2048; size <<= 1) {
      for (int stride = size >> 1; stride >= 256; stride >>= 1) {
        for (int t = tid; t < LL / 2; t += 512) {
          int i = ((t & ~(stride - 1)) << 1) | (t & (stride - 1));
          ce_desc(sh.key, i, i + stride, (i & size) == 0);
        }
        __syncthreads();
      }
      for (int stride = 128; stride > 0; stride >>= 1) {
#pragma unroll
        for (int pp = 0; pp < 2; ++pp) {
          int p = w * 128 + pp * 64 + lane;
          int i = ((p & ~(stride - 1)) << 1) | (p & (stride - 1));
          ce_desc(sh.key, i, i + stride, (i & size) == 0);
        }
        __builtin_amdgcn_wave_barrier();
      }
      __syncthreads();
    }

    const int maxlen = cnt > 1 ? cnt : 1;              // jnp.maximum(cnt,1)
    const unsigned ordNeg1 = ~__float_as_uint(-1.0f);  // ord(-1.0)
    int sv[4]; float mf[4];
#pragma unroll
    for (int k = 0; k < 4; ++k) {
      int j = tid * 4 + k;
      unsigned long long k2 = sh.key[j];
      int idx = (LL - 1) - (int)(unsigned)(k2 & 0xFFFFFFFFull);
      bool masked = ((unsigned)(k2 >> 32)) == ordNeg1;
      bool keep = j < maxlen;
      sv[k] = idx | (masked ? (1 << 11) : 0) | (keep ? (1 << 12) : 0);
      mf[k] = (keep && masked) ? 1.0f : 0.0f;
    }
    s = make_int4(sv[0], sv[1], sv[2], sv[3]);
    ((int4*)(stage + (size_t)b * LL))[tid] = s;
    ((float4*)(mo + (size_t)b * LL))[tid] =
        make_float4(mf[0], mf[1], mf[2], mf[3]);
    __syncthreads();  // vmcnt(0) drain: all threads' stage/mask stores done;
                      // all key[] reads done before ring slots 0,1 overwrite
    if (tid == 0)
      __hip_atomic_store(&flags[b * FLAG_STRIDE], 2, __ATOMIC_RELEASE,
                         __HIP_MEMORY_SCOPE_AGENT);
  } else {
    s = ((const int4*)(stage + (size_t)b * LL))[tid];  // after acquire
  }

  // ---------------- gather: 34 rows, depth-3, 5-slot ring ----------------
  int rslot = 2;  // slot of row rr
  int islot = 0;  // slot of row rr+3
#pragma unroll 1
  for (int rr = 0; rr < NRG; ++rr) {
    // Counted waits. Rows 0-2 were force-drained at the role barrier, so
    // early iterations pass through; steady state: queue before wait is
    // [L(rr),S(rr-3),L(rr+1),S(rr-2),L(rr+2),S(rr-1)] -> vmcnt(5) retires
    // L(rr). Tail: NRG-2 -> 4, NRG-1 -> 3. Never drained to 0.
    if (rr == NRG - 1)      WAITV(3);
    else if (rr == NRG - 2) WAITV(4);
    else                    WAITV(5);
    __builtin_amdgcn_s_barrier();  // all waves' row-rr slices in LDS

    if (rr + 3 < NRG) ISSUE(rr + 3, islot);

    const float* buf = &sh.ring[rslot][0];
    float4 o;
    o.x = (s.x & (1 << 12)) ? buf[s.x & 0x7FF] : 0.0f;
    o.y = (s.y & (1 << 12)) ? buf[s.y & 0x7FF] : 0.0f;
    o.z = (s.z & (1 << 12)) ? buf[s.z & 0x7FF] : 0.0f;
    o.w = (s.w & (1 << 12)) ? buf[s.w & 0x7FF] : 0.0f;
    ((float4*)DSTROW(rr))[tid] = o;

    rslot = (rslot == 4) ? 0 : rslot + 1;
    islot = (islot == 4) ? 0 : islot + 1;
  }
#undef ISSUE
#undef SRCROW
#undef DSTROW
}

// ======================= fallback path (small ws) ==========================
__global__ __launch_bounds__(512) void sortperm_kernel(const void* mask,
                                                       const float* rnd,
                                                       int* stage,
                                                       float* mout) {
  __shared__ unsigned long long key[LL];
  __shared__ int cnt;
  __shared__ unsigned detf;
  const int b = blockIdx.x;
  const int tid = threadIdx.x;
  if (tid == 0) { cnt = 0; detf = 0; }
  __syncthreads();
  {
    unsigned val = ((const unsigned*)mask)[b * 512 + tid];
    unsigned f = (val == 0x3F800000u) ? 2u : (val > 1u ? 1u : 0u);
    if (f) atomicOr(&detf, f);
  }
  __syncthreads();
  const unsigned fl = detf;
  const int layout = (fl & 1u) ? 1 : ((fl & 2u) ? 2 : 0);
  int local = 0;
  for (int l = tid; l < LL; l += 512) {
    bool m;
    if (layout == 1)      m = ((const unsigned char*)mask)[b * LL + l] != 0;
    else if (layout == 2) m = ((const float*)mask)[b * LL + l] != 0.0f;
    else                  m = ((const int*)mask)[b * LL + l] != 0;
    float rf = m ? -1.0f : rnd[b * LL + l];
    unsigned u = __float_as_uint(rf);
    u = (u & 0x80000000u) ? ~u : (u | 0x80000000u);
    key[l] = ((unsigned long long)u << 32) | (unsigned)(LL - 1 - l);
    local += m ? 1 : 0;
  }
  if (local) atomicAdd(&cnt, local);
  __syncthreads();
  const int w = tid >> 6;
  const int lane = tid & 63;
  for (int size = 2; size <= 256; size <<= 1)
    for (int stride = size >> 1; stride > 0; stride >>= 1) {
#pragma unroll
      for (int pp = 0; pp < 2; ++pp) {
        int p = w * 128 + pp * 64 + lane;
        int i = ((p & ~(stride - 1)) << 1) | (p & (stride - 1));
        ce_desc(key, i, i + stride, (i & size) == 0);
      }
      __builtin_amdgcn_wave_barrier();
    }
  __syncthreads();
  for (int size = 512; size <= 2048; size <<= 1) {
    for (int stride = size >> 1; stride >= 256; stride >>= 1) {
      for (int t = tid; t < LL / 2; t += 512) {
        int i = ((t & ~(stride - 1)) << 1) | (t & (stride - 1));
        ce_desc(key, i, i + stride, (i & size) == 0);
      }
      __syncthreads();
    }
    for (int stride = 128; stride > 0; stride >>= 1) {
#pragma unroll
      for (int pp = 0; pp < 2; ++pp) {
        int p = w * 128 + pp * 64 + lane;
        int i = ((p & ~(stride - 1)) << 1) | (p & (stride - 1));
        ce_desc(key, i, i + stride, (i & size) == 0);
      }
      __builtin_amdgcn_wave_barrier();
    }
    __syncthreads();
  }
  const int maxlen = cnt > 1 ? cnt : 1;
  const unsigned ordNeg1 = ~__float_as_uint(-1.0f);
  int sv[4]; float mf[4];
#pragma unroll
  for (int k = 0; k < 4; ++k) {
    int j = tid * 4 + k;
    unsigned long long k2 = key[j];
    int idx = (LL - 1) - (int)(unsigned)(k2 & 0xFFFFFFFFull);
    bool masked = ((unsigned)(k2 >> 32)) == ordNeg1;
    bool keep = j < maxlen;
    sv[k] = idx | (masked ? (1 << 11) : 0) | (keep ? (1 << 12) : 0);
    mf[k] = (keep && masked) ? 1.0f : 0.0f;
  }
  ((int4*)(stage + (size_t)b * LL))[tid] = make_int4(sv[0], sv[1], sv[2], sv[3]);
  if (mout)
    ((float4*)(mout + (size_t)b * LL))[tid] =
        make_float4(mf[0], mf[1], mf[2], mf[3]);
}

__global__ __launch_bounds__(256, 4) void gather_kernel(
    const float* __restrict__ x, const float* __restrict__ v,
    const int* __restrict__ stage, float* __restrict__ xo,
    float* __restrict__ vo) {
  __shared__ float ring[4][LL];
  const int b = blockIdx.x >> 2;
  const int g = blockIdx.x & 3;
  const int tid = threadIdx.x;
  const int w = tid >> 6;
  const int4* st4 = (const int4*)(stage + (size_t)b * LL);
  const int4 s0 = st4[tid];
  const int4 s1 = st4[tid + 256];
  const float* const xs = x + (size_t)b * CC * LL;
  const float* const vs = v + (size_t)b * CVV * LL;
  float* const xd = xo + (size_t)b * CC * LL;
  float* const vd = vo + (size_t)b * CVV * LL;
#define SRCROW(rr) ((g * NRGF + (rr)) < CC \
    ? xs + (size_t)(g * NRGF + (rr)) * LL \
    : vs + (size_t)(g * NRGF + (rr) - CC) * LL)
#define DSTROW(rr) ((g * NRGF + (rr)) < CC \
    ? xd + (size_t)(g * NRGF + (rr)) * LL \
    : vd + (size_t)(g * NRGF + (rr) - CC) * LL)
#define ISSUE(rr) do { \
    const float* _src = SRCROW(rr); \
    float* _base = &ring[(rr) & 3][0] + w * 256; \
    __builtin_amdgcn_global_load_lds( \
        (const __attribute__((address_space(1))) void*)(_src + tid * 4), \
        (__attribute__((address_space(3))) void*)_base, 16, 0, 0); \
    __builtin_amdgcn_global_load_lds( \
        (const __attribute__((address_space(1))) void*)(_src + 1024 + tid * 4), \
        (__attribute__((address_space(3))) void*)(_base + 1024), 16, 0, 0); \
  } while (0)
  ISSUE(0); ISSUE(1); ISSUE(2);
#pragma unroll 1
  for (int rr = 0; rr < NRGF; ++rr) {
    if (rr == 0)              WAITV(4);
    else if (rr == 1)         WAITV(6);
    else if (rr == 2)         WAITV(8);
    else if (rr == NRGF - 2)  WAITV(8);
    else if (rr == NRGF - 1)  WAITV(6);
    else                      WAITV(10);
    __builtin_amdgcn_s_barrier();
    if (rr + 3 < NRGF) ISSUE(rr + 3);
    const float* buf = &ring[rr & 3][0];
    float4 o;
    o.x = (s0.x & (1 << 12)) ? buf[s0.x & 0x7FF] : 0.0f;
    o.y = (s0.y & (1 << 12)) ? buf[s0.y & 0x7FF] : 0.0f;
    o.z = (s0.z & (1 << 12)) ? buf[s0.z & 0x7FF] : 0.0f;
    o.w = (s0.w & (1 << 12)) ? buf[s0.w & 0x7FF] : 0.0f;
    float* dst = DSTROW(rr);
    ((float4*)dst)[tid] = o;
    o.x = (s1.x & (1 << 12)) ? buf[s1.x & 0x7FF] : 0.0f;
    o.y = (s1.y & (1 << 12)) ? buf[s1.y & 0x7FF] : 0.0f;
    o.z = (s1.z & (1 << 12)) ? buf[s1.z & 0x7FF] : 0.0f;
    o.w = (s1.w & (1 << 12)) ? buf[s1.w & 0x7FF] : 0.0f;
    ((float4*)dst)[tid + 256] = o;
  }
#undef ISSUE
#undef SRCROW
#undef DSTROW
}

__global__ __launch_bounds__(256) void maskout_kernel(int* stage, float* mout) {
  const int i = blockIdx.x * 256 + threadIdx.x;
  int s = stage[i];
  mout[i] = ((s & (1 << 12)) && (s & (1 << 11))) ? 1.0f : 0.0f;
}

extern "C" void kernel_launch(void* const* d_in, const int* in_sizes, int n_in,
                              void* d_out, int out_size, void* d_ws, size_t ws_size,
                              hipStream_t stream) {
  const float* x    = (const float*)d_in[0];
  const float* v    = (const float*)d_in[1];
  const void*  mask = d_in[2];
  const float* rnd  = (const float*)d_in[3];

  float* xo = (float*)d_out;                  // B*C*L
  float* vo = xo + (size_t)BB * CC * LL;      // B*CV*L
  float* mo = vo + (size_t)BB * CVV * LL;     // B*1*L

  if (ws_size >= FLAGS_BYTES + STAGE_BYTES) {
    int* flags = (int*)d_ws;
    int* stage = (int*)((char*)d_ws + FLAGS_BYTES);
    hipMemsetAsync(flags, 0, FLAGS_BYTES, stream);
    trimmer_fused<<<BB * NBLK, 512, 0, stream>>>(x, v, mask, rnd, xo, vo, mo,
                                                 stage, flags);
  } else {
    const bool use_ws = ws_size >= STAGE_BYTES;
    int* stage = use_ws ? (int*)d_ws : (int*)mo;
    sortperm_kernel<<<BB, 512, 0, stream>>>(mask, rnd, stage,
                                            use_ws ? mo : nullptr);
    gather_kernel<<<BB * GROUPS, 256, 0, stream>>>(x, v, stage, xo, vo);
    if (!use_ws)
      maskout_kernel<<<(BB * LL) / 256, 256, 0, stream>>>(stage, mo);
  }
}

// Round 8
// 68.167 us; speedup vs baseline: 1.6425x; 1.6425x over previous
//
#include <hip/hip_runtime.h>
#include <stdint.h>

#define BB 256
#define CC 64
#define CVV 4
#define LL 2048
#define NR (CC + CVV)   // 68 rows per block (= per batch)

#define WAITV(n) asm volatile("s_waitcnt vmcnt(" #n ")" ::: "memory")

__device__ __forceinline__ void ce_desc(unsigned long long* key, int i, int j,
                                        bool descBlk) {
  unsigned long long a = key[i], c = key[j];
  bool sw = descBlk ? (a < c) : (a > c);
  if (sw) { key[i] = c; key[j] = a; }
}

// ---------------------------------------------------------------------------
// One block per batch (256 blocks, 1/CU, 512 threads = 8 waves).
// Phase 1 (sort): stable descending argsort of rand_f via bitonic sort of
//   64-bit composite keys ord(rand_f)<<32 | (L-1-idx), wave-segment optimized.
//   Perm entries for this thread's 4 output slots end in an int4 REGISTER —
//   no stage array, no second kernel, no flags. mask_t written directly.
// Phase 2 (gather): 68 rows through an 8-slot LDS ring (64 KB, union'd with
//   the 16 KB key array; slots 2..6 are disjoint from keys, so rows 0..4 are
//   prefetched MID-SORT via global_load_lds and stream under the bitonic).
//   Depth-5 pipeline, counted vmcnt (never drained in-loop), one raw
//   s_barrier per row. Row rr lives in slot (rr+2)&7; reissue target
//   (rr+7)&7 was last read 3 barriers ago -> safe.
// vmcnt counts (in-order retire; queue = loads + row-stores + 1 mask-store):
//   N(rr) = loads_newer(=4 mid) + min(rr,5) + (rr<=4 ? 1:0)
//   -> {0:5, 1:6, 2:7, 3:8, 4..NR-5:9, tail:>=5}. Smaller N = stricter = safe.
// ---------------------------------------------------------------------------
__global__ __launch_bounds__(512) void trimmer_kernel(
    const float* __restrict__ x, const float* __restrict__ v,
    const void* __restrict__ mask, const float* __restrict__ rnd,
    float* __restrict__ xo, float* __restrict__ vo, float* __restrict__ mo) {
  __shared__ union {
    unsigned long long key[LL];   // bytes [0, 16K) = ring slots 0-1
    float ring[8][LL];            // 8 slots x 8 KB = 64 KB
  } sh;
  __shared__ int cnt;
  __shared__ unsigned detf;

  const int b = blockIdx.x;
  const int tid = threadIdx.x;
  const int w = tid >> 6;      // wave 0..7
  const int lane = tid & 63;

  if (tid == 0) { cnt = 0; detf = 0; }
  __syncthreads();

  // --- self-detect bool-mask marshaling from words [b*512, b*512+512) ---
  {
    unsigned val = ((const unsigned*)mask)[b * 512 + tid];
    unsigned f = (val == 0x3F800000u) ? 2u : (val > 1u ? 1u : 0u);
    if (f) atomicOr(&detf, f);
  }
  __syncthreads();
  const unsigned fl = detf;
  const int layout = (fl & 1u) ? 1 : ((fl & 2u) ? 2 : 0);

  // --- build composite keys ---
  int local = 0;
  for (int l = tid; l < LL; l += 512) {
    bool m;
    if (layout == 1)      m = ((const unsigned char*)mask)[b * LL + l] != 0;
    else if (layout == 2) m = ((const float*)mask)[b * LL + l] != 0.0f;
    else                  m = ((const int*)mask)[b * LL + l] != 0;
    float rf = m ? -1.0f : rnd[b * LL + l];
    unsigned u = __float_as_uint(rf);
    u = (u & 0x80000000u) ? ~u : (u | 0x80000000u);  // order-preserving map
    sh.key[l] = ((unsigned long long)u << 32) | (unsigned)(LL - 1 - l);
    local += m ? 1 : 0;
  }
  if (local) atomicAdd(&cnt, local);
  __syncthreads();

  const float* const xs = x + (size_t)b * CC * LL;
  const float* const vs = v + (size_t)b * CVV * LL;
  float* const xd = xo + (size_t)b * CC * LL;
  float* const vd = vo + (size_t)b * CVV * LL;

#define SRCROW(rr) ((rr) < CC ? xs + (size_t)(rr) * LL \
                              : vs + (size_t)((rr) - CC) * LL)
#define DSTROW(rr) ((rr) < CC ? xd + (size_t)(rr) * LL \
                              : vd + (size_t)((rr) - CC) * LL)
  // wave w stages bytes [w*1K, w*1K+1K) of row rr into slot (rr+2)&7
#define ISSUE(rr) do { \
    const float* _src = SRCROW(rr) + w * 256 + lane * 4; \
    float* _dst = &sh.ring[((rr) + 2) & 7][0] + w * 256; \
    __builtin_amdgcn_global_load_lds( \
        (const __attribute__((address_space(1))) void*)_src, \
        (__attribute__((address_space(3))) void*)_dst, 16, 0, 0); \
  } while (0)

  // Prefetch rows 0..4 into slots 2..6 (disjoint from key[]). Issued before
  // the bitonic so the HBM stream ramps under ~5us of sort. The first
  // __syncthreads below them is ~2us later (wave-local phase) -> ~0 stall.
  ISSUE(0); ISSUE(1); ISSUE(2); ISSUE(3); ISSUE(4);

  // --- bitonic sort, descending; wave w owns key[w*256 .. w*256+255] ---
  for (int size = 2; size <= 256; size <<= 1) {
    for (int stride = size >> 1; stride > 0; stride >>= 1) {
#pragma unroll
      for (int pp = 0; pp < 2; ++pp) {
        int p = w * 128 + pp * 64 + lane;
        int i = ((p & ~(stride - 1)) << 1) | (p & (stride - 1));
        ce_desc(sh.key, i, i + stride, (i & size) == 0);
      }
      __builtin_amdgcn_wave_barrier();
    }
  }
  __syncthreads();
  for (int size = 512; size <= 2048; size <<= 1) {
    for (int stride = size >> 1; stride >= 256; stride >>= 1) {
      for (int t = tid; t < LL / 2; t += 512) {
        int i = ((t & ~(stride - 1)) << 1) | (t & (stride - 1));
        ce_desc(sh.key, i, i + stride, (i & size) == 0);
      }
      __syncthreads();
    }
    for (int stride = 128; stride > 0; stride >>= 1) {
#pragma unroll
      for (int pp = 0; pp < 2; ++pp) {
        int p = w * 128 + pp * 64 + lane;
        int i = ((p & ~(stride - 1)) << 1) | (p & (stride - 1));
        ce_desc(sh.key, i, i + stride, (i & size) == 0);
      }
      __builtin_amdgcn_wave_barrier();
    }
    __syncthreads();
  }

  // --- extract perm for output positions 4*tid..4*tid+3 into registers ---
  const int maxlen = cnt > 1 ? cnt : 1;              // jnp.maximum(count, 1)
  const unsigned ordNeg1 = ~__float_as_uint(-1.0f);  // ord(-1.0)
  int sv[4]; float mf[4];
#pragma unroll
  for (int k = 0; k < 4; ++k) {
    int j = tid * 4 + k;
    unsigned long long k2 = sh.key[j];
    int idx = (LL - 1) - (int)(unsigned)(k2 & 0xFFFFFFFFull);
    bool masked = ((unsigned)(k2 >> 32)) == ordNeg1;
    bool keep = j < maxlen;
    sv[k] = idx | (keep ? (1 << 12) : 0);
    mf[k] = (keep && masked) ? 1.0f : 0.0f;
  }
  const int4 s = make_int4(sv[0], sv[1], sv[2], sv[3]);
  ((float4*)(mo + (size_t)b * LL))[tid] = make_float4(mf[0], mf[1], mf[2], mf[3]);
  __syncthreads();  // all key[] reads done before slots 0,1 are overwritten
                    // (also drains the prefetch - one-time, already retired)

  // --- gather: 68 rows, depth-5, 8-slot ring, counted vmcnt ---
#pragma unroll 1
  for (int rr = 0; rr < NR; ++rr) {
    if (rr == 0)            WAITV(5);
    else if (rr == 1)       WAITV(6);
    else if (rr == 2)       WAITV(7);
    else if (rr == 3)       WAITV(8);
    else if (rr >= NR - 4)  WAITV(5);   // conservative tail (actual 8..5)
    else                    WAITV(9);
    __builtin_amdgcn_s_barrier();       // all waves' row-rr slices in LDS

    if (rr + 5 < NR) ISSUE(rr + 5);     // slot (rr+7)&7: last read iter rr-1

    const float* buf = &sh.ring[(rr + 2) & 7][0];
    float4 o;
    o.x = (s.x & (1 << 12)) ? buf[s.x & 0x7FF] : 0.0f;
    o.y = (s.y & (1 << 12)) ? buf[s.y & 0x7FF] : 0.0f;
    o.z = (s.z & (1 << 12)) ? buf[s.z & 0x7FF] : 0.0f;
    o.w = (s.w & (1 << 12)) ? buf[s.w & 0x7FF] : 0.0f;
    ((float4*)DSTROW(rr))[tid] = o;
  }
#undef ISSUE
#undef SRCROW
#undef DSTROW
}

extern "C" void kernel_launch(void* const* d_in, const int* in_sizes, int n_in,
                              void* d_out, int out_size, void* d_ws, size_t ws_size,
                              hipStream_t stream) {
  const float* x    = (const float*)d_in[0];
  const float* v    = (const float*)d_in[1];
  const void*  mask = d_in[2];
  const float* rnd  = (const float*)d_in[3];

  float* xo = (float*)d_out;                  // B*C*L
  float* vo = xo + (size_t)BB * CC * LL;      // B*CV*L
  float* mo = vo + (size_t)BB * CVV * LL;     // B*1*L

  trimmer_kernel<<<BB, 512, 0, stream>>>(x, v, mask, rnd, xo, vo, mo);
}

// Round 9
// 67.359 us; speedup vs baseline: 1.6622x; 1.0120x over previous
//
#include <hip/hip_runtime.h>
#include <stdint.h>

#define BB 256
#define CC 64
#define CVV 4
#define LL 2048
#define NR (CC + CVV)   // 68 rows per block (= per batch)
#define NSLOT 17        // LDS ring slots (8 KB each)
#define PFD 15          // prefetch distance (rows in flight)

#define WAITV(n) asm volatile("s_waitcnt vmcnt(" #n ")" ::: "memory")
// LDS-only barrier: orders ds ops across waves WITHOUT draining vmcnt
// (__syncthreads would emit s_waitcnt vmcnt(0) and kill the prefetch stream).
#define SBAR_LDS() do { \
    asm volatile("s_waitcnt lgkmcnt(0)" ::: "memory"); \
    __builtin_amdgcn_s_barrier(); \
    __builtin_amdgcn_sched_barrier(0); \
  } while (0)

__device__ __forceinline__ void ce_desc(unsigned long long* key, int i, int j,
                                        bool descBlk) {
  unsigned long long a = key[i], c = key[j];
  bool sw = descBlk ? (a < c) : (a > c);
  if (sw) { key[i] = c; key[j] = a; }
}

// ---------------------------------------------------------------------------
// One block per batch (256 blocks = 1/CU, 512 threads = 8 waves).
// Phase 1 (sort): stable descending argsort of rand_f via bitonic sort of
//   composite keys ord(rand_f)<<32 | (L-1-idx). ALL sort barriers are
//   LDS-only (SBAR_LDS) so the 15-row prefetch stream issued before the sort
//   keeps flowing underneath it (~5us of HBM work hidden under ~10us sort).
// Mask-layout detect: 16 block-uniform words -> scalar s_loads (lgkmcnt
//   domain, no vmcnt interaction). byte layout iff acc not in {0,1,1.0f};
//   int32 and float32 layouts collapse into the same (word!=0) test.
// vmem queue per wave (in-order retire): [8 reg loads][L0..L14][S_mask]
//   [per iter rr: L(rr+15), S(rr)]. Newer-than-L(rr):
//   rr<=14: 14 loads + S_mask = 15; 15<=rr<=53: 14+15 = 29; tail >=15.
// Phase 2 (gather): 68 rows, 17-slot ring, prefetch distance 15, one raw
//   s_barrier per row (never draining vmcnt). Row rr sits in slot (rr+2)%17;
//   reissue target at iter rr is slot rr%17, last read in iter rr-2 — two
//   barriers ago, safe.
// ---------------------------------------------------------------------------
__global__ __launch_bounds__(512) void trimmer_kernel(
    const float* __restrict__ x, const float* __restrict__ v,
    const void* __restrict__ mask, const float* __restrict__ rnd,
    float* __restrict__ xo, float* __restrict__ vo, float* __restrict__ mo) {
  __shared__ union {
    unsigned long long key[LL];   // bytes [0,16K) = ring slots 0-1
    float ring[NSLOT][LL];        // 17 x 8 KB = 136 KB
  } sh;
  __shared__ int wcnt[8];

  const int b = blockIdx.x;
  const int tid = threadIdx.x;
  const int w = tid >> 6;      // wave 0..7
  const int lane = tid & 63;
  const unsigned* m32 = (const unsigned*)mask;

  // --- scalar-load layout detect (lgkmcnt domain; ~0 serial cost) ---
  unsigned acc = 0;
#pragma unroll
  for (int j = 0; j < 16; ++j) acc |= m32[(size_t)b * 512 + j];
  const bool is_byte = (acc != 0u) && (acc != 1u) && (acc != 0x3F800000u);

  // --- register loads of rand + mask (BEFORE prefetch issues, so their
  //     consumption waits at vmcnt(15), never draining the prefetch) ---
  float rv[4]; unsigned mw[4];
#pragma unroll
  for (int k = 0; k < 4; ++k) {
    const int l = tid + 512 * k;
    rv[k] = rnd[(size_t)b * LL + l];
    mw[k] = is_byte ? m32[(size_t)b * 512 + (l >> 2)]
                    : m32[(size_t)b * LL + l];
  }
  asm volatile("" ::: "memory");  // pin: reg loads precede the ISSUEs

  const float* const xs = x + (size_t)b * CC * LL;
  const float* const vs = v + (size_t)b * CVV * LL;
  float* const xd = xo + (size_t)b * CC * LL;
  float* const vd = vo + (size_t)b * CVV * LL;

#define SRCROW(rr) ((rr) < CC ? xs + (size_t)(rr) * LL \
                              : vs + (size_t)((rr) - CC) * LL)
#define DSTROW(rr) ((rr) < CC ? xd + (size_t)(rr) * LL \
                              : vd + (size_t)((rr) - CC) * LL)
  // wave w stages bytes [w*1K, w*1K+1K) of a row into the given slot
#define ISSUE(rr, slot) do { \
    const float* _src = SRCROW(rr) + w * 256 + lane * 4; \
    float* _dst = &sh.ring[(slot)][0] + w * 256; \
    __builtin_amdgcn_global_load_lds( \
        (const __attribute__((address_space(1))) void*)_src, \
        (__attribute__((address_space(3))) void*)_dst, 16, 0, 0); \
  } while (0)

  // --- prefetch rows 0..14 into slots 2..16 (disjoint from key[]) ---
#pragma unroll
  for (int k = 0; k < PFD; ++k) ISSUE(k, k + 2);
  asm volatile("" ::: "memory");

  // --- build composite keys (consumes regs at vmcnt(15)) ---
  const int sh8 = 8 * (tid & 3);
  int local = 0;
#pragma unroll
  for (int k = 0; k < 4; ++k) {
    const int l = tid + 512 * k;
    const bool m = is_byte ? (((mw[k] >> sh8) & 0xFFu) != 0u) : (mw[k] != 0u);
    float rf = m ? -1.0f : rv[k];
    unsigned u = __float_as_uint(rf);
    u = (u & 0x80000000u) ? ~u : (u | 0x80000000u);  // order-preserving map
    sh.key[l] = ((unsigned long long)u << 32) | (unsigned)(LL - 1 - l);
    local += m ? 1 : 0;
  }
#pragma unroll
  for (int off = 32; off > 0; off >>= 1) local += __shfl_down(local, off, 64);
  if (lane == 0) wcnt[w] = local;
  SBAR_LDS();

  // --- bitonic sort, descending; wave w owns key[w*256 .. w*256+255] ---
  for (int size = 2; size <= 256; size <<= 1) {
    for (int stride = size >> 1; stride > 0; stride >>= 1) {
#pragma unroll
      for (int pp = 0; pp < 2; ++pp) {
        int p = w * 128 + pp * 64 + lane;
        int i = ((p & ~(stride - 1)) << 1) | (p & (stride - 1));
        ce_desc(sh.key, i, i + stride, (i & size) == 0);
      }
      __builtin_amdgcn_wave_barrier();
    }
  }
  SBAR_LDS();
  for (int size = 512; size <= 2048; size <<= 1) {
    for (int stride = size >> 1; stride >= 256; stride >>= 1) {
      for (int t = tid; t < LL / 2; t += 512) {
        int i = ((t & ~(stride - 1)) << 1) | (t & (stride - 1));
        ce_desc(sh.key, i, i + stride, (i & size) == 0);
      }
      SBAR_LDS();
    }
    for (int stride = 128; stride > 0; stride >>= 1) {
#pragma unroll
      for (int pp = 0; pp < 2; ++pp) {
        int p = w * 128 + pp * 64 + lane;
        int i = ((p & ~(stride - 1)) << 1) | (p & (stride - 1));
        ce_desc(sh.key, i, i + stride, (i & size) == 0);
      }
      __builtin_amdgcn_wave_barrier();
    }
    SBAR_LDS();
  }

  // --- extract perm into registers; write mask_t ---
  const int cnt = wcnt[0] + wcnt[1] + wcnt[2] + wcnt[3] +
                  wcnt[4] + wcnt[5] + wcnt[6] + wcnt[7];
  const int maxlen = cnt > 1 ? cnt : 1;              // jnp.maximum(count, 1)
  const unsigned ordNeg1 = ~__float_as_uint(-1.0f);  // ord(-1.0)
  int sv[4]; float mf[4];
#pragma unroll
  for (int k = 0; k < 4; ++k) {
    const int j = tid * 4 + k;
    unsigned long long k2 = sh.key[j];
    int idx = (LL - 1) - (int)(unsigned)(k2 & 0xFFFFFFFFull);
    bool masked = ((unsigned)(k2 >> 32)) == ordNeg1;
    bool keep = j < maxlen;
    sv[k] = idx | (keep ? (1 << 12) : 0);
    mf[k] = (keep && masked) ? 1.0f : 0.0f;
  }
  const int4 s = make_int4(sv[0], sv[1], sv[2], sv[3]);
  ((float4*)(mo + (size_t)b * LL))[tid] =
      make_float4(mf[0], mf[1], mf[2], mf[3]);   // S_mask in vmem queue
  SBAR_LDS();  // all key[] reads done before slots 0,1 get overwritten

  // --- gather: 68 rows, 17-slot ring, distance-15, counted vmcnt ---
  int rslot = 2;   // slot of row rr
  int islot = 0;   // slot of row rr+PFD
#pragma unroll 1
  for (int rr = 0; rr < NR; ++rr) {
    if (rr <= 14)      WAITV(15);
    else if (rr <= 53) WAITV(29);
    else               WAITV(15);
    __builtin_amdgcn_s_barrier();       // raw: no vmcnt drain
    __builtin_amdgcn_sched_barrier(0);  // pin ds_reads below the barrier

    if (rr + PFD < NR) ISSUE(rr + PFD, islot);
    islot = (islot == NSLOT - 1) ? 0 : islot + 1;

    const float* buf = &sh.ring[rslot][0];
    rslot = (rslot == NSLOT - 1) ? 0 : rslot + 1;
    float4 o;
    o.x = (s.x & (1 << 12)) ? buf[s.x & 0x7FF] : 0.0f;
    o.y = (s.y & (1 << 12)) ? buf[s.y & 0x7FF] : 0.0f;
    o.z = (s.z & (1 << 12)) ? buf[s.z & 0x7FF] : 0.0f;
    o.w = (s.w & (1 << 12)) ? buf[s.w & 0x7FF] : 0.0f;
    ((float4*)DSTROW(rr))[tid] = o;
  }
#undef ISSUE
#undef SRCROW
#undef DSTROW
}

extern "C" void kernel_launch(void* const* d_in, const int* in_sizes, int n_in,
                              void* d_out, int out_size, void* d_ws, size_t ws_size,
                              hipStream_t stream) {
  const float* x    = (const float*)d_in[0];
  const float* v    = (const float*)d_in[1];
  const void*  mask = d_in[2];
  const float* rnd  = (const float*)d_in[3];

  float* xo = (float*)d_out;                  // B*C*L
  float* vo = xo + (size_t)BB * CC * LL;      // B*CV*L
  float* mo = vo + (size_t)BB * CVV * LL;     // B*1*L

  trimmer_kernel<<<BB, 512, 0, stream>>>(x, v, mask, rnd, xo, vo, mo);
}